// Round 9
// baseline (315.216 us; speedup 1.0000x reference)
//
#include <hip/hip_runtime.h>
#include <hip/hip_cooperative_groups.h>
#include <math.h>

namespace cg = cooperative_groups;

#define NT 2048
#define HS 64
#define HNN 256
#define NSTEPS 1000
#define TSTEP 0.01f

typedef unsigned short u16;
typedef __attribute__((ext_vector_type(8))) short bf16x8;
typedef __attribute__((ext_vector_type(4))) float f32x4;

// ws layout (float offsets)
#define OFF_PINV 0         // 64*64
#define OFF_Q    4224      // 2*64
#define OFF_LP   20736     // 1000*64 lam_pow[k][i]
#define OFF_LT   84736     // 64*1000 lamT[i][k]
#define OFF_HT   148736    // bf16 frag region: YH (65536 f) + YL

#define S_H 1028           // k_hidden LDS stage stride

// RNE f32 -> bf16 split: x ~= hi + lo (each bf16), err ~ 2^-18 |x|
__device__ inline void bsplit(float x, u16& hi, u16& lo) {
    unsigned u = __float_as_uint(x);
    unsigned r = (u + 0x7FFFu + ((u >> 16) & 1u)) >> 16;
    hi = (u16)r;
    float xh = __uint_as_float(r << 16);
    float d = x - xh;
    unsigned v = __float_as_uint(d);
    unsigned s = (v + 0x7FFFu + ((v >> 16) & 1u)) >> 16;
    lo = (u16)s;
}

// barrier that waits only LDS ops (lgkm), letting global stores stay in flight
__device__ inline void bar_lds() {
    asm volatile("s_waitcnt lgkmcnt(0)" ::: "memory");
    __builtin_amdgcn_s_barrier();
    asm volatile("" ::: "memory");
}

__device__ inline float tanh_fast(float x) {
    float xc = fminf(fmaxf(x, -15.f), 15.f);
    float a = __builtin_amdgcn_exp2f(xc * 2.885390082f);   // e^{2x}
    return (a - 1.f) * __builtin_amdgcn_rcpf(a + 1.f);
}

union FrontSh {
    struct {
        float Aug[64 * 130];
        float fvec[2][64];
        int   piv[64];
        int   used[64];
    } gj;
    struct {
        float tgt[16][2];
        union { float shT[256 * 17]; float us[16][128]; } u;  // shT dead before us
        float x0s[64 * 17];
        float y0s[64 * 17];
    } y0;
};

// ---------------- k_front: cooperative, 128 blocks x 256 threads ----------------
// phase 1: block0 = pipelined GJ inverse of P; blocks 1-63 lam powers; block 64 Q
// grid.sync
// phase 2: per block ct: hT -> x0 -> y0 (16 cols) -> MFMA frags -> acts(16 targets)
__global__ __launch_bounds__(256) void k_front(const float* __restrict__ P,
                                               const float* __restrict__ D,
                                               const float* __restrict__ lm_w,
                                               const float* __restrict__ target,
                                               const float* __restrict__ l1_w,
                                               const float* __restrict__ l1_b,
                                               const float* __restrict__ l2_w,
                                               const float* __restrict__ l2_b,
                                               const float* __restrict__ lm_b,
                                               float* __restrict__ ws,
                                               float* __restrict__ actions) {
    __shared__ FrontSh sh;
    int b = blockIdx.x;
    int tid = threadIdx.x;

    // ================= phase 1 =================
    if (b == 0) {
        float* Aug = sh.gj.Aug;
        for (int idx = tid; idx < 64 * 128; idx += 256) {
            int r = idx >> 7, c = idx & 127;
            Aug[r * 130 + c] = (c < 64) ? P[r * 64 + c] : ((c - 64) == r ? 1.f : 0.f);
        }
        __syncthreads();

        // prologue: pivot + fvec for column 0
        if (tid < 64) {
            float nv = Aug[tid * 130];
            float v = fabsf(nv); int pi = tid;
            #pragma unroll
            for (int off = 32; off; off >>= 1) {
                float ov = __shfl_xor(v, off);
                int opi = __shfl_xor(pi, off);
                if (ov > v || (ov == v && opi < pi)) { v = ov; pi = opi; }
            }
            float pv = __shfl(nv, pi);
            sh.gj.fvec[0][tid] = (tid == pi) ? 0.f : nv / pv;
            sh.gj.used[tid] = (tid == pi) ? 1 : 0;
            if (tid == 0) sh.gj.piv[0] = pi;
        }
        __syncthreads();

        for (int t = 0; t < 64; ++t) {
            int p = sh.gj.piv[t];
            int par = t & 1;
            if (tid < 64) {
                int col0 = (t < 63) ? (t + 1) : (64 + sh.gj.piv[0]);
                float f = sh.gj.fvec[par][tid];
                float src = Aug[p * 130 + col0];
                float nv = Aug[tid * 130 + col0] - f * src;
                Aug[tid * 130 + col0] = nv;
                if (t < 63) {
                    float v = sh.gj.used[tid] ? -1.f : fabsf(nv);
                    int pi = tid;
                    #pragma unroll
                    for (int off = 32; off; off >>= 1) {
                        float ov = __shfl_xor(v, off);
                        int opi = __shfl_xor(pi, off);
                        if (ov > v || (ov == v && opi < pi)) { v = ov; pi = opi; }
                    }
                    float pv = __shfl(nv, pi);
                    sh.gj.fvec[par ^ 1][tid] = (tid == pi) ? 0.f : nv / pv;
                    if (tid == pi) sh.gj.used[tid] = 1;
                    if (tid == 0) sh.gj.piv[t + 1] = pi;
                }
            } else {
                int w = (tid >> 6) - 1;          // 0..2
                int lane = tid & 63;
                float f = sh.gj.fvec[par][lane];
                const float* rowp = Aug + p * 130;
                float* rowr = Aug + lane * 130;
                int pcnt = 63 - t;
                for (int s = 1 + w; s < 64; s += 3) {
                    int col = (s < pcnt) ? (t + 1 + s) : (64 + sh.gj.piv[s - pcnt]);
                    rowr[col] -= f * rowp[col];
                }
            }
            __syncthreads();
        }

        for (int idx = tid; idx < 4096; idx += 256) {
            int j = idx >> 6, m = idx & 63;
            int pr = sh.gj.piv[j];
            ws[OFF_PINV + j * 64 + m] = Aug[pr * 130 + 64 + m] / Aug[pr * 130 + j];
        }
    } else if (b <= 63) {
        int base = ((b - 1) * 256 + tid) * 4;
        #pragma unroll
        for (int m = 0; m < 4; ++m) {
            int id = base + m;
            if (id < NSTEPS * 64) {
                int k = id >> 6, i = id & 63;
                float l = 1.0f - TSTEP * expf(D[i]);
                float pw = exp2f((float)k * log2f(l));
                ws[OFF_LP + id] = pw;
                ws[OFF_LT + i * NSTEPS + k] = pw;
            }
        }
    } else if (b == 64) {
        if (tid < 128) {
            int a = tid >> 6, i = tid & 63;
            float s = 0.f;
            for (int r = 0; r < 64; ++r) s = fmaf(lm_w[a * 64 + r], P[r * 64 + i], s);
            ws[OFF_Q + tid] = s;
        }
    }

    cg::this_grid().sync();

    // ================= phase 2: blocks 0..127 =================
    int ct = b;
    int cbase = ct * 16;

    if (tid < 16) {
        float2 tv = ((const float2*)target)[cbase + tid];
        sh.y0.tgt[tid][0] = tv.x; sh.y0.tgt[tid][1] = tv.y;
    }
    __syncthreads();
    {   // hT row j = tid, 16 local columns
        float w0 = l1_w[2 * tid], w1 = l1_w[2 * tid + 1], bb = l1_b[tid];
        #pragma unroll
        for (int cc = 0; cc < 16; ++cc)
            sh.y0.u.shT[tid * 17 + cc] =
                fmaxf(fmaf(w0, sh.y0.tgt[cc][0], fmaf(w1, sh.y0.tgt[cc][1], bb)), 0.f);
    }
    __syncthreads();
    int i = tid >> 2, cs = (tid & 3) * 4;
    {   // x0[i][c] = l2_w[i,:] @ hT[:,c] + l2_b[i]
        const float* l2wi = l2_w + i * 256;
        float bb = l2_b[i];
        float a0 = bb, a1 = bb, a2 = bb, a3 = bb;
        #pragma unroll 4
        for (int j = 0; j < 256; ++j) {
            float w = l2wi[j];
            const float* s = sh.y0.u.shT + j * 17 + cs;
            a0 = fmaf(w, s[0], a0); a1 = fmaf(w, s[1], a1);
            a2 = fmaf(w, s[2], a2); a3 = fmaf(w, s[3], a3);
        }
        sh.y0.x0s[i * 17 + cs + 0] = a0; sh.y0.x0s[i * 17 + cs + 1] = a1;
        sh.y0.x0s[i * 17 + cs + 2] = a2; sh.y0.x0s[i * 17 + cs + 3] = a3;
    }
    __syncthreads();
    {   // y0[i][c] = Pinv[i,:] @ x0[:,c]
        const float* Pinvi = ws + OFF_PINV + i * 64;
        float a0 = 0, a1 = 0, a2 = 0, a3 = 0;
        #pragma unroll 4
        for (int m = 0; m < 64; ++m) {
            float pv = Pinvi[m];
            const float* s = sh.y0.x0s + m * 17 + cs;
            a0 = fmaf(pv, s[0], a0); a1 = fmaf(pv, s[1], a1);
            a2 = fmaf(pv, s[2], a2); a3 = fmaf(pv, s[3], a3);
        }
        sh.y0.y0s[i * 17 + cs + 0] = a0; sh.y0.y0s[i * 17 + cs + 1] = a1;
        sh.y0.y0s[i * 17 + cs + 2] = a2; sh.y0.y0s[i * 17 + cs + 3] = a3;
    }
    __syncthreads();

    // us[cg][t] = Q[a][i] * y0s[i][cg]   (aliases dead shT region)
    for (int idx = tid; idx < 2048; idx += 256) {
        int cgi = idx >> 7, t = idx & 127;
        int a = t >> 6, ii = t & 63;
        sh.y0.u.us[cgi][t] = ws[OFF_Q + a * 64 + ii] * sh.y0.y0s[ii * 17 + cgi];
    }
    // MFMA frags (layout k_hidden expects)
    if (tid < 128) {
        int kt = tid >> 6, lane = tid & 63;
        int c_l = lane & 15;
        int i0 = kt * 32 + (lane >> 4) * 8;
        u16* YH = (u16*)(ws + OFF_HT);
        u16* YL = YH + 131072;
        bf16x8 vh, vl;
        #pragma unroll
        for (int j = 0; j < 8; ++j) {
            u16 h, lo;
            bsplit(sh.y0.y0s[(i0 + j) * 17 + c_l], h, lo);
            vh[j] = (short)h; vl[j] = (short)lo;
        }
        int off = ((ct * 2 + kt) * 64 + lane);
        *(bf16x8*)(YH + off * 8) = vh;
        *(bf16x8*)(YL + off * 8) = vl;
    }
    __syncthreads();

    // acts for this block's 16 targets, 4 target-chunks of 4 (32 accum VGPRs)
    if (tid < 250) {
        int k0 = tid * 4;
        float b0 = lm_b[0], b1 = lm_b[1];
        const float* lamT = ws + OFF_LT;
        #pragma unroll 1
        for (int ch = 0; ch < 4; ++ch) {
            int cg0 = ch * 4;
            float4 s[4][2];
            #pragma unroll
            for (int j = 0; j < 4; ++j) {
                s[j][0] = make_float4(b0, b0, b0, b0);
                s[j][1] = make_float4(b1, b1, b1, b1);
            }
            #pragma unroll 4
            for (int ii = 0; ii < 64; ++ii) {
                float4 v = *(const float4*)&lamT[ii * NSTEPS + k0];
                #pragma unroll
                for (int j = 0; j < 4; ++j) {
                    float u0 = sh.y0.u.us[cg0 + j][ii];
                    float u1 = sh.y0.u.us[cg0 + j][64 + ii];
                    s[j][0].x = fmaf(u0, v.x, s[j][0].x);
                    s[j][0].y = fmaf(u0, v.y, s[j][0].y);
                    s[j][0].z = fmaf(u0, v.z, s[j][0].z);
                    s[j][0].w = fmaf(u0, v.w, s[j][0].w);
                    s[j][1].x = fmaf(u1, v.x, s[j][1].x);
                    s[j][1].y = fmaf(u1, v.y, s[j][1].y);
                    s[j][1].z = fmaf(u1, v.z, s[j][1].z);
                    s[j][1].w = fmaf(u1, v.w, s[j][1].w);
                }
            }
            #pragma unroll
            for (int j = 0; j < 4; ++j)
                #pragma unroll
                for (int a = 0; a < 2; ++a) {
                    float4 r;
                    r.x = tanh_fast(s[j][a].x);
                    r.y = tanh_fast(s[j][a].y);
                    r.z = tanh_fast(s[j][a].z);
                    r.w = tanh_fast(s[j][a].w);
                    *(float4*)(actions + (size_t)(cbase + cg0 + j) * 2000 + a * 1000 + k0) = r;
                }
        }
    }
}

// ---------------- main: hidden[k] = (P diag(lam^k)) @ y0, split-bf16 MFMA ----------
// identical to round 5-8 (~107 us) except nontemporal dump stores.
__global__ __launch_bounds__(512, 2) void k_hidden(const float* __restrict__ P,
                                                   const float* __restrict__ ws,
                                                   float* __restrict__ hidden) {
    int k = blockIdx.x;
    int tid = threadIdx.x;
    int wid = tid >> 6, lane = tid & 63;
    int l15 = lane & 15, lg = lane >> 4;

    extern __shared__ float stage[];   // 16 * S_H floats = 65792 B

    const u16* YH = (const u16*)(ws + OFF_HT);
    const u16* YL = YH + 131072;
    const float* lp = ws + OFF_LP + k * 64;

    bf16x8 ah[4][2], al[4][2];
    #pragma unroll
    for (int rt = 0; rt < 4; ++rt) {
        int r = rt * 16 + l15;
        #pragma unroll
        for (int kt = 0; kt < 2; ++kt) {
            int i0 = kt * 32 + lg * 8;
            #pragma unroll
            for (int j = 0; j < 8; ++j) {
                float v = P[r * 64 + i0 + j] * lp[i0 + j];
                u16 h, lo;
                bsplit(v, h, lo);
                ah[rt][kt][j] = (short)h;
                al[rt][kt][j] = (short)lo;
            }
        }
    }

    float* outk = hidden + (size_t)k * 64 * NT;

    #pragma unroll 1
    for (int half = 0; half < 2; ++half) {
        bf16x8 bh[8][2], bl[8][2];
        #pragma unroll
        for (int q = 0; q < 8; ++q)
            #pragma unroll
            for (int kt = 0; kt < 2; ++kt) {
                int ct_g = half * 64 + wid * 8 + q;
                int off = ((ct_g * 2 + kt) * 64 + lane) * 8;
                bh[q][kt] = *(const bf16x8*)(YH + off);
                bl[q][kt] = *(const bf16x8*)(YL + off);
            }
        #pragma unroll
        for (int rt = 0; rt < 4; ++rt) {
            #pragma unroll
            for (int q = 0; q < 8; ++q) {
                f32x4 acc = {0.f, 0.f, 0.f, 0.f};
                #pragma unroll
                for (int kt = 0; kt < 2; ++kt) {
                    acc = __builtin_amdgcn_mfma_f32_16x16x32_bf16(ah[rt][kt], bh[q][kt], acc, 0, 0, 0);
                    acc = __builtin_amdgcn_mfma_f32_16x16x32_bf16(al[rt][kt], bh[q][kt], acc, 0, 0, 0);
                    acc = __builtin_amdgcn_mfma_f32_16x16x32_bf16(ah[rt][kt], bl[q][kt], acc, 0, 0, 0);
                }
                int col = wid * 128 + q * 16 + l15;
                #pragma unroll
                for (int reg = 0; reg < 4; ++reg)
                    stage[(lg * 4 + reg) * S_H + col] = acc[reg];
            }
            bar_lds();
            #pragma unroll
            for (int it = 0; it < 8; ++it) {
                int f = it * 512 + tid;            // float4 index, 0..4095
                int r = f >> 8, c4 = f & 255;
                f32x4 v = *(const f32x4*)&stage[r * S_H + (c4 << 2)];
                __builtin_nontemporal_store(v,
                    (f32x4*)(outk + (size_t)(rt * 16 + r) * NT + half * 1024 + (c4 << 2)));
            }
            bar_lds();
        }
    }
}

extern "C" void kernel_launch(void* const* d_in, const int* in_sizes, int n_in,
                              void* d_out, int out_size, void* d_ws, size_t ws_size,
                              hipStream_t stream) {
    const float* target = (const float*)d_in[0];
    const float* D      = (const float*)d_in[1];
    const float* P      = (const float*)d_in[2];
    const float* l1_w   = (const float*)d_in[3];
    const float* l1_b   = (const float*)d_in[4];
    const float* l2_w   = (const float*)d_in[5];
    const float* l2_b   = (const float*)d_in[6];
    const float* lm_w   = (const float*)d_in[7];
    const float* lm_b   = (const float*)d_in[8];
    float* ws = (float*)d_ws;
    float* actions = (float*)d_out;                  // 2048*2*1000
    float* hidden  = (float*)d_out + 4096000;        // 1000*64*2048

    hipFuncSetAttribute((const void*)k_hidden,
                        hipFuncAttributeMaxDynamicSharedMemorySize, 16 * S_H * 4);

    void* args[] = { (void*)&P, (void*)&D, (void*)&lm_w, (void*)&target,
                     (void*)&l1_w, (void*)&l1_b, (void*)&l2_w, (void*)&l2_b,
                     (void*)&lm_b, (void*)&ws, (void*)&actions };
    hipLaunchCooperativeKernel((const void*)k_front, dim3(128), dim3(256),
                               args, 0, stream);
    hipLaunchKernelGGL(k_hidden, dim3(1000), dim3(512), 16 * S_H * 4, stream, P, ws, hidden);
}

// Round 10
// 307.695 us; speedup vs baseline: 1.0244x; 1.0244x over previous
//
#include <hip/hip_runtime.h>
#include <math.h>

#define NT 2048
#define HS 64
#define HNN 256
#define NSTEPS 1000
#define TSTEP 0.01f

typedef unsigned short u16;
typedef __attribute__((ext_vector_type(8))) short bf16x8;
typedef __attribute__((ext_vector_type(4))) float f32x4;

// ws layout (float offsets)
#define OFF_PINV 0         // 64*64
#define OFF_Q    4224      // 2*64
#define OFF_LP   20736     // 1000*64 lam_pow[k][i]
#define OFF_LT   84736     // 64*1000 lamT[i][k]
#define OFF_HT   148736    // bf16 frag region: YH (65536 f) + YL

#define S_H 1028           // k_hidden LDS stage stride

// RNE f32 -> bf16 split: x ~= hi + lo (each bf16), err ~ 2^-18 |x|
__device__ inline void bsplit(float x, u16& hi, u16& lo) {
    unsigned u = __float_as_uint(x);
    unsigned r = (u + 0x7FFFu + ((u >> 16) & 1u)) >> 16;
    hi = (u16)r;
    float xh = __uint_as_float(r << 16);
    float d = x - xh;
    unsigned v = __float_as_uint(d);
    unsigned s = (v + 0x7FFFu + ((v >> 16) & 1u)) >> 16;
    lo = (u16)s;
}

// barrier that waits only LDS ops (lgkm), letting global stores stay in flight
__device__ inline void bar_lds() {
    asm volatile("s_waitcnt lgkmcnt(0)" ::: "memory");
    __builtin_amdgcn_s_barrier();
    asm volatile("" ::: "memory");
}

__device__ inline float tanh_fast(float x) {
    float xc = fminf(fmaxf(x, -15.f), 15.f);
    float a = __builtin_amdgcn_exp2f(xc * 2.885390082f);   // e^{2x}
    return (a - 1.f) * __builtin_amdgcn_rcpf(a + 1.f);
}

// ---------------- k_pre: IDENTICAL to round 8 (launched x2 as A/A probe) --------
__global__ __launch_bounds__(512) void k_pre(const float* __restrict__ P,
                                             const float* __restrict__ D,
                                             const float* __restrict__ lm_w,
                                             float* __restrict__ ws) {
    int b = blockIdx.x;
    int tid = threadIdx.x;
    if (b == 0) {
        __shared__ float Aug[64 * 130];
        __shared__ float fvec[2][64];
        __shared__ int s_piv[64];
        __shared__ int used[64];

        for (int idx = tid; idx < 64 * 128; idx += 512) {
            int r = idx >> 7, c = idx & 127;
            Aug[r * 130 + c] = (c < 64) ? P[r * 64 + c] : ((c - 64) == r ? 1.f : 0.f);
        }
        __syncthreads();

        if (tid < 64) {
            float nv = Aug[tid * 130];
            float v = fabsf(nv); int pi = tid;
            #pragma unroll
            for (int off = 32; off; off >>= 1) {
                float ov = __shfl_xor(v, off);
                int opi = __shfl_xor(pi, off);
                if (ov > v || (ov == v && opi < pi)) { v = ov; pi = opi; }
            }
            float pv = __shfl(nv, pi);
            fvec[0][tid] = (tid == pi) ? 0.f : nv / pv;
            used[tid] = (tid == pi) ? 1 : 0;
            if (tid == 0) s_piv[0] = pi;
        }
        __syncthreads();

        for (int t = 0; t < 64; ++t) {
            int p = s_piv[t];
            int par = t & 1;
            if (tid < 64) {
                int col0 = (t < 63) ? (t + 1) : (64 + s_piv[0]);
                float f = fvec[par][tid];
                float src = Aug[p * 130 + col0];
                float nv = Aug[tid * 130 + col0] - f * src;
                Aug[tid * 130 + col0] = nv;
                if (t < 63) {
                    float v = used[tid] ? -1.f : fabsf(nv);
                    int pi = tid;
                    #pragma unroll
                    for (int off = 32; off; off >>= 1) {
                        float ov = __shfl_xor(v, off);
                        int opi = __shfl_xor(pi, off);
                        if (ov > v || (ov == v && opi < pi)) { v = ov; pi = opi; }
                    }
                    float pv = __shfl(nv, pi);
                    fvec[par ^ 1][tid] = (tid == pi) ? 0.f : nv / pv;
                    if (tid == pi) used[tid] = 1;
                    if (tid == 0) s_piv[t + 1] = pi;
                }
            } else {
                int w = (tid >> 6) - 1;          // 0..6
                int lane = tid & 63;
                float f = fvec[par][lane];
                const float* rowp = Aug + p * 130;
                float* rowr = Aug + lane * 130;
                int pcnt = 63 - t;
                for (int s = 1 + w; s < 64; s += 7) {
                    int col = (s < pcnt) ? (t + 1 + s) : (64 + s_piv[s - pcnt]);
                    rowr[col] -= f * rowp[col];
                }
            }
            __syncthreads();
        }

        for (int idx = tid; idx < 4096; idx += 512) {
            int j = idx >> 6, m = idx & 63;
            int pr = s_piv[j];
            ws[OFF_PINV + j * 64 + m] = Aug[pr * 130 + 64 + m] / Aug[pr * 130 + j];
        }
    } else if (b <= 32) {
        int base = ((b - 1) * 512 + tid) * 4;
        #pragma unroll
        for (int m = 0; m < 4; ++m) {
            int id = base + m;
            if (id < NSTEPS * 64) {
                int k = id >> 6, i = id & 63;
                float l = 1.0f - TSTEP * expf(D[i]);
                float pw = exp2f((float)k * log2f(l));
                ws[OFF_LP + id] = pw;
                ws[OFF_LT + i * NSTEPS + k] = pw;
            }
        }
    } else {
        if (tid < 128) {
            int a = tid >> 6, i = tid & 63;
            float s = 0.f;
            for (int r = 0; r < 64; ++r) s = fmaf(lm_w[a * 64 + r], P[r * 64 + i], s);
            ws[OFF_Q + tid] = s;
        }
    }
}

// ---------------- k_y0fa: per 16-col block: hT -> x0 -> y0 -> frags + acts -------
__global__ __launch_bounds__(256) void k_y0fa(const float* __restrict__ target,
                                              const float* __restrict__ l1_w,
                                              const float* __restrict__ l1_b,
                                              const float* __restrict__ l2_w,
                                              const float* __restrict__ l2_b,
                                              const float* __restrict__ lm_b,
                                              float* __restrict__ ws,
                                              float* __restrict__ actions) {
    int ct = blockIdx.x;                 // 0..127
    int cbase = ct * 16;
    int tid = threadIdx.x;
    __shared__ float tgt[16][2];
    __shared__ union { float shT[256 * 17]; float us[16][128]; } u;  // shT dead before us
    __shared__ float x0s[64 * 17];
    __shared__ float y0s[64 * 17];

    if (tid < 16) {
        float2 tv = ((const float2*)target)[cbase + tid];
        tgt[tid][0] = tv.x; tgt[tid][1] = tv.y;
    }
    __syncthreads();
    {   // hT row j = tid, 16 local columns
        float w0 = l1_w[2 * tid], w1 = l1_w[2 * tid + 1], bb = l1_b[tid];
        #pragma unroll
        for (int cc = 0; cc < 16; ++cc)
            u.shT[tid * 17 + cc] =
                fmaxf(fmaf(w0, tgt[cc][0], fmaf(w1, tgt[cc][1], bb)), 0.f);
    }
    __syncthreads();
    int i = tid >> 2, cs = (tid & 3) * 4;
    {   // x0[i][c] = l2_w[i,:] @ hT[:,c] + l2_b[i]
        const float* l2wi = l2_w + i * 256;
        float bb = l2_b[i];
        float a0 = bb, a1 = bb, a2 = bb, a3 = bb;
        #pragma unroll 4
        for (int j = 0; j < 256; ++j) {
            float w = l2wi[j];
            const float* s = u.shT + j * 17 + cs;
            a0 = fmaf(w, s[0], a0); a1 = fmaf(w, s[1], a1);
            a2 = fmaf(w, s[2], a2); a3 = fmaf(w, s[3], a3);
        }
        x0s[i * 17 + cs + 0] = a0; x0s[i * 17 + cs + 1] = a1;
        x0s[i * 17 + cs + 2] = a2; x0s[i * 17 + cs + 3] = a3;
    }
    __syncthreads();
    {   // y0[i][c] = Pinv[i,:] @ x0[:,c]
        const float* Pinvi = ws + OFF_PINV + i * 64;
        float a0 = 0, a1 = 0, a2 = 0, a3 = 0;
        #pragma unroll 4
        for (int m = 0; m < 64; ++m) {
            float pv = Pinvi[m];
            const float* s = x0s + m * 17 + cs;
            a0 = fmaf(pv, s[0], a0); a1 = fmaf(pv, s[1], a1);
            a2 = fmaf(pv, s[2], a2); a3 = fmaf(pv, s[3], a3);
        }
        y0s[i * 17 + cs + 0] = a0; y0s[i * 17 + cs + 1] = a1;
        y0s[i * 17 + cs + 2] = a2; y0s[i * 17 + cs + 3] = a3;
    }
    __syncthreads();

    // us[cg][t] = Q[a][i] * y0s[i][cg]   (aliases dead shT region)
    for (int idx = tid; idx < 2048; idx += 256) {
        int cgi = idx >> 7, t = idx & 127;
        int a = t >> 6, ii = t & 63;
        u.us[cgi][t] = ws[OFF_Q + a * 64 + ii] * y0s[ii * 17 + cgi];
    }
    // MFMA frags (layout k_hidden expects)
    if (tid < 128) {
        int kt = tid >> 6, lane = tid & 63;
        int c_l = lane & 15;
        int i0 = kt * 32 + (lane >> 4) * 8;
        u16* YH = (u16*)(ws + OFF_HT);
        u16* YL = YH + 131072;
        bf16x8 vh, vl;
        #pragma unroll
        for (int j = 0; j < 8; ++j) {
            u16 h, lo;
            bsplit(y0s[(i0 + j) * 17 + c_l], h, lo);
            vh[j] = (short)h; vl[j] = (short)lo;
        }
        int off = ((ct * 2 + kt) * 64 + lane);
        *(bf16x8*)(YH + off * 8) = vh;
        *(bf16x8*)(YL + off * 8) = vl;
    }
    __syncthreads();

    // acts for this block's 16 targets, 4 chunks of 4 targets
    if (tid < 250) {
        int k0 = tid * 4;
        float b0 = lm_b[0], b1 = lm_b[1];
        const float* lamT = ws + OFF_LT;
        #pragma unroll 1
        for (int ch = 0; ch < 4; ++ch) {
            int cg0 = ch * 4;
            float4 s[4][2];
            #pragma unroll
            for (int j = 0; j < 4; ++j) {
                s[j][0] = make_float4(b0, b0, b0, b0);
                s[j][1] = make_float4(b1, b1, b1, b1);
            }
            #pragma unroll 4
            for (int ii = 0; ii < 64; ++ii) {
                float4 v = *(const float4*)&lamT[ii * NSTEPS + k0];
                #pragma unroll
                for (int j = 0; j < 4; ++j) {
                    float u0 = u.us[cg0 + j][ii];
                    float u1 = u.us[cg0 + j][64 + ii];
                    s[j][0].x = fmaf(u0, v.x, s[j][0].x);
                    s[j][0].y = fmaf(u0, v.y, s[j][0].y);
                    s[j][0].z = fmaf(u0, v.z, s[j][0].z);
                    s[j][0].w = fmaf(u0, v.w, s[j][0].w);
                    s[j][1].x = fmaf(u1, v.x, s[j][1].x);
                    s[j][1].y = fmaf(u1, v.y, s[j][1].y);
                    s[j][1].z = fmaf(u1, v.z, s[j][1].z);
                    s[j][1].w = fmaf(u1, v.w, s[j][1].w);
                }
            }
            #pragma unroll
            for (int j = 0; j < 4; ++j)
                #pragma unroll
                for (int a = 0; a < 2; ++a) {
                    float4 r;
                    r.x = tanh_fast(s[j][a].x);
                    r.y = tanh_fast(s[j][a].y);
                    r.z = tanh_fast(s[j][a].z);
                    r.w = tanh_fast(s[j][a].w);
                    *(float4*)(actions + (size_t)(cbase + cg0 + j) * 2000 + a * 1000 + k0) = r;
                }
        }
    }
}

// ---------------- main: hidden[k] = (P diag(lam^k)) @ y0, split-bf16 MFMA --------
// round-8 exact (regular stores; NT reverted)
__global__ __launch_bounds__(512, 2) void k_hidden(const float* __restrict__ P,
                                                   const float* __restrict__ ws,
                                                   float* __restrict__ hidden) {
    int k = blockIdx.x;
    int tid = threadIdx.x;
    int wid = tid >> 6, lane = tid & 63;
    int l15 = lane & 15, lg = lane >> 4;

    extern __shared__ float stage[];   // 16 * S_H floats = 65792 B

    const u16* YH = (const u16*)(ws + OFF_HT);
    const u16* YL = YH + 131072;
    const float* lp = ws + OFF_LP + k * 64;

    bf16x8 ah[4][2], al[4][2];
    #pragma unroll
    for (int rt = 0; rt < 4; ++rt) {
        int r = rt * 16 + l15;
        #pragma unroll
        for (int kt = 0; kt < 2; ++kt) {
            int i0 = kt * 32 + lg * 8;
            #pragma unroll
            for (int j = 0; j < 8; ++j) {
                float v = P[r * 64 + i0 + j] * lp[i0 + j];
                u16 h, lo;
                bsplit(v, h, lo);
                ah[rt][kt][j] = (short)h;
                al[rt][kt][j] = (short)lo;
            }
        }
    }

    float* outk = hidden + (size_t)k * 64 * NT;

    #pragma unroll 1
    for (int half = 0; half < 2; ++half) {
        bf16x8 bh[8][2], bl[8][2];
        #pragma unroll
        for (int q = 0; q < 8; ++q)
            #pragma unroll
            for (int kt = 0; kt < 2; ++kt) {
                int ct_g = half * 64 + wid * 8 + q;
                int off = ((ct_g * 2 + kt) * 64 + lane) * 8;
                bh[q][kt] = *(const bf16x8*)(YH + off);
                bl[q][kt] = *(const bf16x8*)(YL + off);
            }
        #pragma unroll
        for (int rt = 0; rt < 4; ++rt) {
            #pragma unroll
            for (int q = 0; q < 8; ++q) {
                f32x4 acc = {0.f, 0.f, 0.f, 0.f};
                #pragma unroll
                for (int kt = 0; kt < 2; ++kt) {
                    acc = __builtin_amdgcn_mfma_f32_16x16x32_bf16(ah[rt][kt], bh[q][kt], acc, 0, 0, 0);
                    acc = __builtin_amdgcn_mfma_f32_16x16x32_bf16(al[rt][kt], bh[q][kt], acc, 0, 0, 0);
                    acc = __builtin_amdgcn_mfma_f32_16x16x32_bf16(ah[rt][kt], bl[q][kt], acc, 0, 0, 0);
                }
                int col = wid * 128 + q * 16 + l15;
                #pragma unroll
                for (int reg = 0; reg < 4; ++reg)
                    stage[(lg * 4 + reg) * S_H + col] = acc[reg];
            }
            bar_lds();
            #pragma unroll
            for (int it = 0; it < 8; ++it) {
                int f = it * 512 + tid;            // float4 index, 0..4095
                int r = f >> 8, c4 = f & 255;
                float4 v = *(const float4*)&stage[r * S_H + (c4 << 2)];
                *(float4*)(outk + (size_t)(rt * 16 + r) * NT + half * 1024 + (c4 << 2)) = v;
            }
            bar_lds();
        }
    }
}

extern "C" void kernel_launch(void* const* d_in, const int* in_sizes, int n_in,
                              void* d_out, int out_size, void* d_ws, size_t ws_size,
                              hipStream_t stream) {
    const float* target = (const float*)d_in[0];
    const float* D      = (const float*)d_in[1];
    const float* P      = (const float*)d_in[2];
    const float* l1_w   = (const float*)d_in[3];
    const float* l1_b   = (const float*)d_in[4];
    const float* l2_w   = (const float*)d_in[5];
    const float* l2_b   = (const float*)d_in[6];
    const float* lm_w   = (const float*)d_in[7];
    const float* lm_b   = (const float*)d_in[8];
    float* ws = (float*)d_ws;
    float* actions = (float*)d_out;                  // 2048*2*1000
    float* hidden  = (float*)d_out + 4096000;        // 1000*64*2048

    hipFuncSetAttribute((const void*)k_hidden,
                        hipFuncAttributeMaxDynamicSharedMemorySize, 16 * S_H * 4);

    // A/A probe on k_pre: marginal of 2nd launch = T(k_pre)
    hipLaunchKernelGGL(k_pre,    dim3(34),   dim3(512), 0, stream, P, D, lm_w, ws);
    hipLaunchKernelGGL(k_pre,    dim3(34),   dim3(512), 0, stream, P, D, lm_w, ws);
    hipLaunchKernelGGL(k_y0fa,   dim3(128),  dim3(256), 0, stream, target, l1_w, l1_b, l2_w, l2_b, lm_b, ws, actions);
    hipLaunchKernelGGL(k_hidden, dim3(1000), dim3(512), 16 * S_H * 4, stream, P, ws, hidden);
}

// Round 11
// 201.799 us; speedup vs baseline: 1.5620x; 1.5248x over previous
//
#include <hip/hip_runtime.h>
#include <math.h>

#define NT 2048
#define HS 64
#define HNN 256
#define NSTEPS 1000
#define TSTEP 0.01f

typedef unsigned short u16;
typedef __attribute__((ext_vector_type(8))) short bf16x8;
typedef __attribute__((ext_vector_type(4))) float f32x4;

// ws layout (float offsets)
#define OFF_PINV 0         // 64*64  (approximate inverse R; refined per-block)
#define OFF_HT   148736    // bf16 frag region: YH (65536 f) + YL

#define S_H 1028           // k_hidden LDS stage stride

// RNE f32 -> bf16 split: x ~= hi + lo (each bf16), err ~ 2^-18 |x|
__device__ inline void bsplit(float x, u16& hi, u16& lo) {
    unsigned u = __float_as_uint(x);
    unsigned r = (u + 0x7FFFu + ((u >> 16) & 1u)) >> 16;
    hi = (u16)r;
    float xh = __uint_as_float(r << 16);
    float d = x - xh;
    unsigned v = __float_as_uint(d);
    unsigned s = (v + 0x7FFFu + ((v >> 16) & 1u)) >> 16;
    lo = (u16)s;
}

// barrier that waits only LDS ops (lgkm), letting global stores stay in flight
__device__ inline void bar_lds() {
    asm volatile("s_waitcnt lgkmcnt(0)" ::: "memory");
    __builtin_amdgcn_s_barrier();
    asm volatile("" ::: "memory");
}

__device__ inline float tanh_fast(float x) {
    float xc = fminf(fmaxf(x, -15.f), 15.f);
    float a = __builtin_amdgcn_exp2f(xc * 2.885390082f);   // e^{2x}
    return (a - 1.f) * __builtin_amdgcn_rcpf(a + 1.f);
}

// ---------------- k_gj: single block, NO-PIVOT pipelined Gauss-Jordan -> R ------
// 1 barrier/iter; wave0 updates col t+1 and derives fvec_{t+1}; waves 1-7 update
// the other 63 active columns. Accuracy repaired by refinement in k_y0fa.
__global__ __launch_bounds__(512) void k_gj(const float* __restrict__ P,
                                            float* __restrict__ ws) {
    __shared__ float Aug[64 * 130];
    __shared__ float fvec[2][64];
    int tid = threadIdx.x;

    for (int idx = tid; idx < 64 * 128; idx += 512) {
        int r = idx >> 7, c = idx & 127;
        Aug[r * 130 + c] = (c < 64) ? P[r * 64 + c] : ((c - 64) == r ? 1.f : 0.f);
    }
    __syncthreads();

    // prologue: fvec for column 0 (pivot row = 0)
    if (tid < 64) {
        float nv = Aug[tid * 130];
        float pv = __shfl(nv, 0);
        fvec[0][tid] = (tid == 0) ? 0.f : nv / pv;
    }
    __syncthreads();

    for (int t = 0; t < 64; ++t) {
        int par = t & 1;
        if (tid < 64) {
            int col0 = (t < 63) ? (t + 1) : 64;      // at t=63: I-col 0
            float f = fvec[par][tid];
            float src = Aug[t * 130 + col0];         // pivot row = t (broadcast)
            float nv = Aug[tid * 130 + col0] - f * src;
            Aug[tid * 130 + col0] = nv;
            if (t < 63) {
                float pv = __shfl(nv, t + 1);
                fvec[par ^ 1][tid] = (tid == (t + 1)) ? 0.f : nv / pv;
            }
        } else {
            int w = (tid >> 6) - 1;                  // 0..6
            int lane = tid & 63;
            float f = fvec[par][lane];
            const float* rowp = Aug + t * 130;
            float* rowr = Aug + lane * 130;
            int pcnt = 63 - t;                       // remaining P-part cols
            for (int s = 1 + w; s < 64; s += 7) {
                int col = (s < pcnt) ? (t + 1 + s) : (64 + (s - pcnt));
                rowr[col] -= f * rowp[col];
            }
        }
        __syncthreads();
    }

    // extraction with deferred row scaling (piv[j] = j)
    for (int idx = tid; idx < 4096; idx += 512) {
        int j = idx >> 6, m = idx & 63;
        ws[OFF_PINV + j * 64 + m] = Aug[j * 130 + 64 + m] / Aug[j * 130 + j];
    }
}

// ---------------- k_y0fa: per 16-col block, 512 thr -------------------------------
// hT -> x0 -> y=R x0 -> 2x iterative refinement (y += R(x0-Py)) -> frags + acts.
// Q and lambda recomputed in-block (no tables, no extra kernels).
__global__ __launch_bounds__(512) void k_y0fa(const float* __restrict__ target,
                                              const float* __restrict__ l1_w,
                                              const float* __restrict__ l1_b,
                                              const float* __restrict__ l2_w,
                                              const float* __restrict__ l2_b,
                                              const float* __restrict__ lm_w,
                                              const float* __restrict__ lm_b,
                                              const float* __restrict__ D,
                                              const float* __restrict__ P,
                                              float* __restrict__ ws,
                                              float* __restrict__ actions) {
    int ct = blockIdx.x;                 // 0..127
    int cbase = ct * 16;
    int tid = threadIdx.x;
    __shared__ float tgt[16][2];
    __shared__ union { float shT[256 * 17]; float rs[64 * 17]; float us[16][128]; } u;
    __shared__ float x0s[64 * 17];
    __shared__ float y0s[64 * 17];
    __shared__ float lam_s[64], l2l_s[64];
    __shared__ float Q_s[128];

    if (tid < 16) {
        float2 tv = ((const float2*)target)[cbase + tid];
        tgt[tid][0] = tv.x; tgt[tid][1] = tv.y;
    } else if (tid >= 64 && tid < 128) {
        int i = tid - 64;
        float l = 1.0f - TSTEP * expf(D[i]);
        lam_s[i] = l;
        l2l_s[i] = log2f(l);
    } else if (tid >= 128 && tid < 256) {
        int t = tid - 128;                     // Q[a][i] = sum_r lm_w[a][r] P[r][i]
        int a = t >> 6, i = t & 63;
        float s = 0.f;
        for (int r = 0; r < 64; ++r) s = fmaf(lm_w[a * 64 + r], P[r * 64 + i], s);
        Q_s[t] = s;
    }
    __syncthreads();
    if (tid < 256) {   // hT row j = tid, 16 local columns
        float w0 = l1_w[2 * tid], w1 = l1_w[2 * tid + 1], bb = l1_b[tid];
        #pragma unroll
        for (int cc = 0; cc < 16; ++cc)
            u.shT[tid * 17 + cc] =
                fmaxf(fmaf(w0, tgt[cc][0], fmaf(w1, tgt[cc][1], bb)), 0.f);
    }
    __syncthreads();
    int i = tid >> 3, cs = (tid & 7) * 2;      // each thread: row i, 2 cols
    {   // x0[i][c] = l2_w[i,:] @ hT[:,c] + l2_b[i]
        const float* l2wi = l2_w + i * 256;
        float bb = l2_b[i];
        float a0 = bb, a1 = bb;
        #pragma unroll 4
        for (int j = 0; j < 256; ++j) {
            float w = l2wi[j];
            a0 = fmaf(w, u.shT[j * 17 + cs], a0);
            a1 = fmaf(w, u.shT[j * 17 + cs + 1], a1);
        }
        x0s[i * 17 + cs] = a0; x0s[i * 17 + cs + 1] = a1;
    }
    __syncthreads();
    const float* Ri = ws + OFF_PINV + i * 64;
    {   // y = R @ x0
        float b0 = 0, b1 = 0;
        #pragma unroll 4
        for (int m = 0; m < 64; ++m) {
            float rv = Ri[m];
            b0 = fmaf(rv, x0s[m * 17 + cs], b0);
            b1 = fmaf(rv, x0s[m * 17 + cs + 1], b1);
        }
        y0s[i * 17 + cs] = b0; y0s[i * 17 + cs + 1] = b1;
    }
    __syncthreads();
    // 2x iterative refinement: y += R (x0 - P y)
    const float* Pi = P + i * 64;
    #pragma unroll 1
    for (int it = 0; it < 2; ++it) {
        float r0 = x0s[i * 17 + cs], r1 = x0s[i * 17 + cs + 1];
        #pragma unroll 4
        for (int m = 0; m < 64; ++m) {
            float pv = Pi[m];
            r0 = fmaf(-pv, y0s[m * 17 + cs], r0);
            r1 = fmaf(-pv, y0s[m * 17 + cs + 1], r1);
        }
        u.rs[i * 17 + cs] = r0; u.rs[i * 17 + cs + 1] = r1;
        __syncthreads();
        float d0 = 0, d1 = 0;
        #pragma unroll 4
        for (int m = 0; m < 64; ++m) {
            float rv = Ri[m];
            d0 = fmaf(rv, u.rs[m * 17 + cs], d0);
            d1 = fmaf(rv, u.rs[m * 17 + cs + 1], d1);
        }
        y0s[i * 17 + cs] += d0; y0s[i * 17 + cs + 1] += d1;
        __syncthreads();
    }

    // us[cg][t] = Q[t] * y0s[i(t)][cg]   (overwrites dead rs/shT)
    for (int idx = tid; idx < 2048; idx += 512) {
        int cgi = idx >> 7, t = idx & 127;
        u.us[cgi][t] = Q_s[t] * y0s[(t & 63) * 17 + cgi];
    }
    // MFMA frags (layout k_hidden expects)
    if (tid < 128) {
        int kt = tid >> 6, lane = tid & 63;
        int c_l = lane & 15;
        int i0 = kt * 32 + (lane >> 4) * 8;
        u16* YH = (u16*)(ws + OFF_HT);
        u16* YL = YH + 131072;
        bf16x8 vh, vl;
        #pragma unroll
        for (int j = 0; j < 8; ++j) {
            u16 h, lo;
            bsplit(y0s[(i0 + j) * 17 + c_l], h, lo);
            vh[j] = (short)h; vl[j] = (short)lo;
        }
        int off = ((ct * 2 + kt) * 64 + lane);
        *(bf16x8*)(YH + off * 8) = vh;
        *(bf16x8*)(YL + off * 8) = vl;
    }
    __syncthreads();

    // acts: 500 threads, 2 k-values each, 4 chunks of 4 targets
    if (tid < 500) {
        int k0 = tid * 2;
        float b0 = lm_b[0], b1 = lm_b[1];
        float fk0 = (float)k0;
        #pragma unroll 1
        for (int ch = 0; ch < 4; ++ch) {
            int cg0 = ch * 4;
            float2 s[4][2];
            #pragma unroll
            for (int j = 0; j < 4; ++j) {
                s[j][0] = make_float2(b0, b0);
                s[j][1] = make_float2(b1, b1);
            }
            #pragma unroll 4
            for (int ii = 0; ii < 64; ++ii) {
                float p0 = __builtin_amdgcn_exp2f(fk0 * l2l_s[ii]);
                float p1 = p0 * lam_s[ii];
                #pragma unroll
                for (int j = 0; j < 4; ++j) {
                    float u0 = u.us[cg0 + j][ii];
                    float u1 = u.us[cg0 + j][64 + ii];
                    s[j][0].x = fmaf(u0, p0, s[j][0].x);
                    s[j][0].y = fmaf(u0, p1, s[j][0].y);
                    s[j][1].x = fmaf(u1, p0, s[j][1].x);
                    s[j][1].y = fmaf(u1, p1, s[j][1].y);
                }
            }
            #pragma unroll
            for (int j = 0; j < 4; ++j)
                #pragma unroll
                for (int a = 0; a < 2; ++a) {
                    float2 r;
                    r.x = tanh_fast(s[j][a].x);
                    r.y = tanh_fast(s[j][a].y);
                    *(float2*)(actions + (size_t)(cbase + cg0 + j) * 2000 + a * 1000 + k0) = r;
                }
        }
    }
}

// ---------------- main: hidden[k] = (P diag(lam^k)) @ y0, split-bf16 MFMA --------
// round-8 structure (~107 us); lam^k now computed in-block from D (no LP table)
__global__ __launch_bounds__(512, 2) void k_hidden(const float* __restrict__ P,
                                                   const float* __restrict__ D,
                                                   const float* __restrict__ ws,
                                                   float* __restrict__ hidden) {
    int k = blockIdx.x;
    int tid = threadIdx.x;
    int wid = tid >> 6, lane = tid & 63;
    int l15 = lane & 15, lg = lane >> 4;

    extern __shared__ float stage[];   // 16 * S_H floats = 65792 B
    __shared__ float lp_s[64];

    const u16* YH = (const u16*)(ws + OFF_HT);
    const u16* YL = YH + 131072;

    if (tid < 64) {
        float l = 1.0f - TSTEP * expf(D[tid]);
        lp_s[tid] = exp2f((float)k * log2f(l));
    }
    __syncthreads();

    bf16x8 ah[4][2], al[4][2];
    #pragma unroll
    for (int rt = 0; rt < 4; ++rt) {
        int r = rt * 16 + l15;
        #pragma unroll
        for (int kt = 0; kt < 2; ++kt) {
            int i0 = kt * 32 + lg * 8;
            #pragma unroll
            for (int j = 0; j < 8; ++j) {
                float v = P[r * 64 + i0 + j] * lp_s[i0 + j];
                u16 h, lo;
                bsplit(v, h, lo);
                ah[rt][kt][j] = (short)h;
                al[rt][kt][j] = (short)lo;
            }
        }
    }

    float* outk = hidden + (size_t)k * 64 * NT;

    #pragma unroll 1
    for (int half = 0; half < 2; ++half) {
        bf16x8 bh[8][2], bl[8][2];
        #pragma unroll
        for (int q = 0; q < 8; ++q)
            #pragma unroll
            for (int kt = 0; kt < 2; ++kt) {
                int ct_g = half * 64 + wid * 8 + q;
                int off = ((ct_g * 2 + kt) * 64 + lane) * 8;
                bh[q][kt] = *(const bf16x8*)(YH + off);
                bl[q][kt] = *(const bf16x8*)(YL + off);
            }
        #pragma unroll
        for (int rt = 0; rt < 4; ++rt) {
            #pragma unroll
            for (int q = 0; q < 8; ++q) {
                f32x4 acc = {0.f, 0.f, 0.f, 0.f};
                #pragma unroll
                for (int kt = 0; kt < 2; ++kt) {
                    acc = __builtin_amdgcn_mfma_f32_16x16x32_bf16(ah[rt][kt], bh[q][kt], acc, 0, 0, 0);
                    acc = __builtin_amdgcn_mfma_f32_16x16x32_bf16(al[rt][kt], bh[q][kt], acc, 0, 0, 0);
                    acc = __builtin_amdgcn_mfma_f32_16x16x32_bf16(ah[rt][kt], bl[q][kt], acc, 0, 0, 0);
                }
                int col = wid * 128 + q * 16 + l15;
                #pragma unroll
                for (int reg = 0; reg < 4; ++reg)
                    stage[(lg * 4 + reg) * S_H + col] = acc[reg];
            }
            bar_lds();
            #pragma unroll
            for (int it = 0; it < 8; ++it) {
                int f = it * 512 + tid;            // float4 index, 0..4095
                int r = f >> 8, c4 = f & 255;
                float4 v = *(const float4*)&stage[r * S_H + (c4 << 2)];
                *(float4*)(outk + (size_t)(rt * 16 + r) * NT + half * 1024 + (c4 << 2)) = v;
            }
            bar_lds();
        }
    }
}

extern "C" void kernel_launch(void* const* d_in, const int* in_sizes, int n_in,
                              void* d_out, int out_size, void* d_ws, size_t ws_size,
                              hipStream_t stream) {
    const float* target = (const float*)d_in[0];
    const float* D      = (const float*)d_in[1];
    const float* P      = (const float*)d_in[2];
    const float* l1_w   = (const float*)d_in[3];
    const float* l1_b   = (const float*)d_in[4];
    const float* l2_w   = (const float*)d_in[5];
    const float* l2_b   = (const float*)d_in[6];
    const float* lm_w   = (const float*)d_in[7];
    const float* lm_b   = (const float*)d_in[8];
    float* ws = (float*)d_ws;
    float* actions = (float*)d_out;                  // 2048*2*1000
    float* hidden  = (float*)d_out + 4096000;        // 1000*64*2048

    hipFuncSetAttribute((const void*)k_hidden,
                        hipFuncAttributeMaxDynamicSharedMemorySize, 16 * S_H * 4);

    hipLaunchKernelGGL(k_gj,     dim3(1),    dim3(512), 0, stream, P, ws);
    hipLaunchKernelGGL(k_y0fa,   dim3(128),  dim3(512), 0, stream,
                       target, l1_w, l1_b, l2_w, l2_b, lm_w, lm_b, D, P, ws, actions);
    hipLaunchKernelGGL(k_hidden, dim3(1000), dim3(512), 16 * S_H * 4, stream, P, D, ws, hidden);
}